// Round 14
// baseline (53.851 us; speedup 1.0000x reference)
//
#include <hip/hip_runtime.h>
#include <hip/hip_bf16.h>

typedef __attribute__((ext_vector_type(8))) short short8;
typedef __attribute__((ext_vector_type(4))) float f32x4;

#define NC    91
#define DM    64
#define CIN   128
#define NMOV  4206
#define MR    96
#define HP    68      // hbuf fp32 pitch
#define NT    1024
#define NW    16
#define VTP   104     // vT pitch (j dim, shorts)

// d_ws bf16 weight offsets (in shorts)
#define W_EMBED 0
#define W_IN    8192
#define W_OUT   20480
#define W_FF1   24576
#define W_FF2   32768
#define W_FT    40960
#define W_TOTAL 49152

__constant__ int HEXOFF[NC] = {
  55,66,77,88,99,110,
  45,56,67,78,89,100,111,
  35,46,57,68,79,90,101,112,
  25,36,47,58,69,80,91,102,113,
  15,26,37,48,59,70,81,92,103,114,
  5,16,27,38,49,60,71,82,93,104,115,
  6,17,28,39,50,61,72,83,94,105,
  7,18,29,40,51,62,73,84,95,
  8,19,30,41,52,63,74,85,
  9,20,31,42,53,64,75,
  10,21,32,43,54,65
};

#define SWZ(row, col, PB) ((row)*(PB) + ((((((col)*2)>>4)) ^ ((row)&7)) << 4) + (((col)*2)&15))

__device__ __forceinline__ short f2bf(float f) {
  __hip_bfloat16 h = __float2bfloat16(f);
  return __builtin_bit_cast(short, h);
}

__device__ __forceinline__ short8 ldfrag128(const short* buf, int row, int k0) {
  return *(const short8*)((const char*)buf + SWZ(row, k0, 128));
}
__device__ __forceinline__ short8 ldfrag256(const short* buf, int row, int k0) {
  return *(const short8*)((const char*)buf + SWZ(row, k0, 256));
}
__device__ __forceinline__ void stb16_128(short* buf, int row, int col, float v) {
  *(short*)((char*)buf + SWZ(row, col, 128)) = f2bf(v);
}
// 16B copy from bf16 ws (row-major, K cols) into swizzled LDS slot
__device__ __forceinline__ void cp8_swz(short* dst, int PB, const short* src, int r, int c8, int K) {
  short8 v = *(const short8*)(src + r*K + c8*8);
  *(short8*)((char*)dst + r*PB + ((c8 ^ (r&7)) << 4)) = v;
}

// 16-lane-group LayerNorm -> ab16 bf16 (swz PB=128)
__device__ __forceinline__ void ln_group(const float* hbuf, short* ab16,
                                         const float* gw, const float* gb,
                                         int wid, int lane) {
  const int sub = lane >> 4;
  const int l16 = lane & 15;
  const float4 g4 = *(const float4*)&gw[l16*4];
  const float4 b4 = *(const float4*)&gb[l16*4];
  for (int g = wid; g < 23; g += NW) {
    int i = g*4 + sub;
    if (i < NC) {
      float4 v = *(const float4*)&hbuf[i*HP + l16*4];
      float s  = (v.x + v.y) + (v.z + v.w);
      float sq = fmaf(v.x,v.x, fmaf(v.y,v.y, fmaf(v.z,v.z, v.w*v.w)));
      #pragma unroll
      for (int off = 1; off < 16; off <<= 1) {
        s  += __shfl_xor(s, off, 64);
        sq += __shfl_xor(sq, off, 64);
      }
      float m  = s * (1.0f/64.0f);
      float vr = sq * (1.0f/64.0f) - m*m;
      float rs = rsqrtf(vr + 1e-5f);
      short4 o;
      o.x = f2bf((v.x - m)*rs*g4.x + b4.x);
      o.y = f2bf((v.y - m)*rs*g4.y + b4.y);
      o.z = f2bf((v.z - m)*rs*g4.z + b4.z);
      o.w = f2bf((v.w - m)*rs*g4.w + b4.w);
      *(short4*)((char*)ab16 + i*128 + (((l16>>1) ^ (i&7))<<4) + (l16&1)*8) = o;
    }
  }
}

__global__ __launch_bounds__(256)
void prep_w(const float* __restrict__ embed_w, const float* __restrict__ in_w,
            const float* __restrict__ out_w, const float* __restrict__ ff1_w,
            const float* __restrict__ ff2_w, const float* __restrict__ from_w,
            const float* __restrict__ to_w, short* __restrict__ ws)
{
  int i = blockIdx.x*256 + threadIdx.x;
  if (i >= W_TOTAL) return;
  float v;
  if      (i < 8192)  v = embed_w[i];
  else if (i < 20480) v = in_w[i - 8192];
  else if (i < 24576) v = out_w[i - 20480];
  else if (i < 32768) v = ff1_w[i - 24576];
  else if (i < 40960) v = ff2_w[i - 32768];
  else if (i < 45056) v = from_w[i - 40960];
  else                v = to_w[i - 45056];
  ws[i] = f2bf(v);
}

__global__ __launch_bounds__(1024, 1)
void policy_fused(
    const float* __restrict__ x,
    const float* __restrict__ embed_b, const float* __restrict__ pos,
    const float* __restrict__ in_b,  const float* __restrict__ out_b,
    const float* __restrict__ ln1_g, const float* __restrict__ ln1_b,
    const float* __restrict__ ln2_g, const float* __restrict__ ln2_b,
    const float* __restrict__ ff1_b, const float* __restrict__ ff2_b,
    const float* __restrict__ from_b, const float* __restrict__ to_b,
    const float* __restrict__ move_bias,
    const int* __restrict__ move_from, const int* __restrict__ move_to,
    const short* __restrict__ ws,
    float* __restrict__ out)
{
  __shared__ float arena[18816];     // 75264B: feats/pall-lo/qf/kf/out_w-stage/f1/G
  __shared__ float hbuf[MR*HP];      // 26112B: residual h ; F,T alias after P8
  __shared__ short ab16[MR*64];      // 12288B: LN out / attn out
  __shared__ short wAll[20480];      // 40960B: embed,in_w / vtb,pall-hi / ff1,ff2,ft
  __shared__ float lsum[384];        // 1536B: softmax row sums     => 156160B

  const int tid  = threadIdx.x;
  const int lane = tid & 63;
  const int wid  = tid >> 6;
  const int l15  = lane & 15;
  const int kfr  = (lane >> 4) * 8;
  const int mfr  = (lane >> 4) * 4;
  const int b    = blockIdx.x;
  const float* xb = x + (size_t)b * (CIN*121);

  short* arena_s = (short*)arena;
  short* featsb = arena_s;                 // [96][128] bf16 swz256 (shorts 0..12288)
  short* qf     = arena_s + 24576;         // frag-linear q [4][6][32][8] (6144)
  short* kf     = arena_s + 30720;         // frag-linear k (6144)
  short* vtb    = wAll;                    // [4][16][VTP] V^T (6656, over dead embed)
  short* owst   = arena_s + 24576;         // out_w stage swz128 (4096, over dead qf)
  short* f1     = arena_s + 18432;         // [96][128] bf16 swz256 (12288)
  float* G      = arena;                   // [96][96] fp32

  // pall: row i (768B): rows 0..63 in arena, 64..95 over dead in_w in wAll
  #define PALL_ROW(i) ((char*)((i) < 64 ? (void*)((char*)arena + (i)*768) \
                                        : (void*)((char*)wAll + 16384 + ((i)-64)*768)))

  // ---- P0: feats gather -> bf16 ; stage embed_w+in_w ; zero lsum+tails ----
  for (int e = tid; e < 16*NC; e += NT) {
    int c0 = e / NC, i = e - c0*NC;
    float v[8];
    #pragma unroll
    for (int u = 0; u < 8; ++u) v[u] = xb[(c0*8 + u)*121 + HEXOFF[i]];
    short8 s8;
    #pragma unroll
    for (int u = 0; u < 8; ++u) s8[u] = f2bf(v[u]);
    *(short8*)((char*)featsb + i*256 + ((c0 ^ (i&7)) << 4)) = s8;
  }
  if (tid < 320) ((unsigned*)featsb)[5824 + tid] = 0;   // zero feats rows 91..95
  if (tid < 384) lsum[tid] = 0.f;
  for (int e = tid; e < 1024; e += NT) {                // embed_w [64][128] swz256
    int r = e >> 4, c8 = e & 15;
    cp8_swz(wAll, 256, ws + W_EMBED, r, c8, 128);
  }
  for (int e = tid; e < 1536; e += NT) {                // in_w [192][64] swz128
    int r = e >> 3, c8 = e & 7;
    cp8_swz(wAll + 8192, 128, ws + W_IN, r, c8, 64);
  }
  __syncthreads();

  // ---- P1: embed MFMA (K=128) -> hbuf ----
  for (int t = wid; t < 24; t += NW) {
    int mt = t >> 2, nt = t & 3;
    int ar = mt*16 + l15, br = nt*16 + l15;
    f32x4 acc = {0.f,0.f,0.f,0.f};
    #pragma unroll
    for (int kk = 0; kk < 4; ++kk) {
      short8 a = ldfrag256(featsb, ar, kk*32 + kfr);
      short8 w = ldfrag256(wAll,   br, kk*32 + kfr);
      acc = __builtin_amdgcn_mfma_f32_16x16x32_bf16(a, w, acc, 0, 0, 0);
    }
    int col = nt*16 + l15;
    float eb = embed_b[col];
    #pragma unroll
    for (int i2 = 0; i2 < 4; ++i2) {
      int m = mt*16 + mfr + i2;
      float p = (m < NC) ? pos[m*DM + col] : 0.f;
      hbuf[m*HP + col] = acc[i2] + eb + p;
    }
  }
  __syncthreads();

  // ---- P2: zero ab16 tail + LN1 -> ab16 ----
  if (tid < 160) ((unsigned*)ab16)[2912 + tid] = 0;
  ln_group(hbuf, ab16, ln1_g, ln1_b, wid, lane);
  __syncthreads();

  // ---- P3: qkv MFMA (N=192,K=64) -> DIRECT qf(*CS)/kf/vtb ; zero vtb pad ----
  {
    const float CS = 0.25f * 1.4426950408889634f;
    for (int t = wid; t < 72; t += NW) {
      int mt = t / 12, nt = t - mt*12;
      int ar = mt*16 + l15, br = nt*16 + l15;
      f32x4 acc = {0.f,0.f,0.f,0.f};
      #pragma unroll
      for (int kk = 0; kk < 2; ++kk) {
        short8 a = ldfrag128(ab16,        ar, kk*32 + kfr);
        short8 w = ldfrag128(wAll + 8192, br, kk*32 + kfr);
        acc = __builtin_amdgcn_mfma_f32_16x16x32_bf16(a, w, acc, 0, 0, 0);
      }
      int col = nt*16 + l15;
      float bia = in_b[col];
      int h = (col & 63) >> 4;
      int d = col & 15;
      if (nt < 4) {               // q, scaled
        int base = (h*6 + mt)*32 + ((d >= 8) ? 16 : 0);
        #pragma unroll
        for (int i2 = 0; i2 < 4; ++i2)
          qf[(base + mfr + i2)*8 + (d & 7)] = f2bf((acc[i2] + bia) * CS);
      } else if (nt < 8) {        // k
        int base = (h*6 + mt)*32 + ((d >= 8) ? 16 : 0);
        #pragma unroll
        for (int i2 = 0; i2 < 4; ++i2)
          kf[(base + mfr + i2)*8 + (d & 7)] = f2bf(acc[i2] + bia);
      } else {                    // v transposed
        #pragma unroll
        for (int i2 = 0; i2 < 4; ++i2) {
          int m = mt*16 + mfr + i2;
          if (m < NC) vtb[(h*16 + d)*VTP + m] = f2bf(acc[i2] + bia);
        }
      }
    }
    for (int e = tid; e < 832; e += NT) {   // zero vtb cols 91..103
      int r = e / 13, c = e - r*13;
      vtb[r*VTP + NC + c] = 0;
    }
  }
  __syncthreads();

  // ---- P4: S MFMA (A=kf, B=qf) -> P=exp2(S) -> pall ; fused row sums ----
  {
    const short8 zfrag = {0,0,0,0,0,0,0,0};
    for (int t = wid; t < 144; t += NW) {
      int h = t / 36, r = t - h*36;
      int it = r / 6, jt = r - it*6;
      short8 a = zfrag, w = zfrag;
      if (lane < 32) {
        a = *(const short8*)(kf + ((h*6 + jt)*32 + lane)*8);  // A row = j
        w = *(const short8*)(qf + ((h*6 + it)*32 + lane)*8);  // B row = i
      }
      f32x4 acc = {0.f,0.f,0.f,0.f};
      acc = __builtin_amdgcn_mfma_f32_16x16x32_bf16(a, w, acc, 0, 0, 0);
      int i  = it*16 + l15;
      int jb = jt*16 + mfr;
      float p0 = exp2f(acc[0]), p1 = exp2f(acc[1]);
      float p2 = exp2f(acc[2]), p3 = exp2f(acc[3]);
      float psum = ((jb+0) < NC ? p0 : 0.f) + ((jb+1) < NC ? p1 : 0.f)
                 + ((jb+2) < NC ? p2 : 0.f) + ((jb+3) < NC ? p3 : 0.f);
      psum += __shfl_xor(psum, 16, 64);
      psum += __shfl_xor(psum, 32, 64);
      if (lane < 16) atomicAdd(&lsum[h*96 + i], psum);
      short4 p4;
      p4.x = f2bf(p0); p4.y = f2bf(p1); p4.z = f2bf(p2); p4.w = f2bf(p3);
      *(short4*)(PALL_ROW(i) + ((((h*96 + jb)*2)) ^ ((i&7) << 4))) = p4;
    }
  }
  __syncthreads();

  // ---- P5: PV MFMA (A=vtb, B=pall) -> o/lsum -> ab16 ; stage out_w ----
  for (int e = tid; e < 512; e += NT) {                 // out_w [64][64] -> owst swz128
    int r = e >> 3, c8 = e & 7;
    cp8_swz(owst, 128, ws + W_OUT, r, c8, 64);
  }
  for (int t = wid; t < 24; t += NW) {
    int h = t & 3, it = t >> 2;
    int i = it*16 + l15;
    const char* prow = PALL_ROW(i);
    f32x4 acc = {0.f,0.f,0.f,0.f};
    #pragma unroll
    for (int kk = 0; kk < 3; ++kk) {
      int k0 = kk*32 + kfr;
      short8 a = *(const short8*)(vtb + (h*16 + l15)*VTP + k0);
      short8 w = *(const short8*)(prow + (((h*96 + k0)*2) ^ ((i&7) << 4)));
      acc = __builtin_amdgcn_mfma_f32_16x16x32_bf16(a, w, acc, 0, 0, 0);
    }
    float li = 1.0f / lsum[h*96 + i];
    short4 o4;
    o4.x = f2bf(acc[0] * li); o4.y = f2bf(acc[1] * li);
    o4.z = f2bf(acc[2] * li); o4.w = f2bf(acc[3] * li);
    *(short4*)((char*)ab16 + SWZ(i, h*16 + mfr, 128)) = o4;
  }
  __syncthreads();

  // ---- P5b: out-proj MFMA: hbuf += o @ out_w^T + out_b ; stage ff1 ----
  for (int e = tid; e < 1024; e += NT) {                // ff1 [128][64] -> wAll swz128
    int r = e >> 3, c8 = e & 7;
    cp8_swz(wAll, 128, ws + W_FF1, r, c8, 64);
  }
  for (int t = wid; t < 24; t += NW) {
    int mt = t >> 2, nt = t & 3;
    int ar = mt*16 + l15, br = nt*16 + l15;
    f32x4 acc = {0.f,0.f,0.f,0.f};
    #pragma unroll
    for (int kk = 0; kk < 2; ++kk) {
      short8 a = ldfrag128(ab16, ar, kk*32 + kfr);
      short8 w = ldfrag128(owst, br, kk*32 + kfr);
      acc = __builtin_amdgcn_mfma_f32_16x16x32_bf16(a, w, acc, 0, 0, 0);
    }
    int col = nt*16 + l15;
    float ob = out_b[col];
    #pragma unroll
    for (int i2 = 0; i2 < 4; ++i2) {
      int m = mt*16 + mfr + i2;
      hbuf[m*HP + col] += acc[i2] + ob;
    }
  }
  __syncthreads();

  // ---- P6: LN2 -> ab16 ----
  ln_group(hbuf, ab16, ln2_g, ln2_b, wid, lane);
  __syncthreads();

  // ---- P7: ff1 MFMA -> f1 bf16 swz256 ; stage ff2 ----
  for (int e = tid; e < 1024; e += NT) {                // ff2 [64][128] -> wAll+8192 swz256
    int r = e >> 4, c8 = e & 15;
    cp8_swz(wAll + 8192, 256, ws + W_FF2, r, c8, 128);
  }
  for (int t = wid; t < 48; t += NW) {
    int mt = t >> 3, nt = t & 7;
    int ar = mt*16 + l15, br = nt*16 + l15;
    f32x4 acc = {0.f,0.f,0.f,0.f};
    #pragma unroll
    for (int kk = 0; kk < 2; ++kk) {
      short8 a = ldfrag128(ab16, ar, kk*32 + kfr);
      short8 w = ldfrag128(wAll, br, kk*32 + kfr);
      acc = __builtin_amdgcn_mfma_f32_16x16x32_bf16(a, w, acc, 0, 0, 0);
    }
    int col = nt*16 + l15;
    float bia = ff1_b[col];
    #pragma unroll
    for (int i2 = 0; i2 < 4; ++i2) {
      int m = mt*16 + mfr + i2;
      *(short*)((char*)f1 + SWZ(m, col, 256)) = f2bf(fmaxf(acc[i2] + bia, 0.f));
    }
  }
  __syncthreads();

  // ---- P8: ff2 MFMA (K=128): ab16 = bf16(h + f1@W^T + b) ; stage from/to ----
  for (int e = tid; e < 1024; e += NT) {                // from/to [128][64] -> wAll swz128
    int r = e >> 3, c8 = e & 7;
    cp8_swz(wAll, 128, ws + W_FT, r, c8, 64);
  }
  for (int t = wid; t < 24; t += NW) {
    int mt = t >> 2, nt = t & 3;
    int ar = mt*16 + l15, br = nt*16 + l15;
    f32x4 acc = {0.f,0.f,0.f,0.f};
    #pragma unroll
    for (int kk = 0; kk < 4; ++kk) {
      short8 a = ldfrag256(f1,          ar, kk*32 + kfr);
      short8 w = ldfrag256(wAll + 8192, br, kk*32 + kfr);
      acc = __builtin_amdgcn_mfma_f32_16x16x32_bf16(a, w, acc, 0, 0, 0);
    }
    int col = nt*16 + l15;
    float bia = ff2_b[col];
    #pragma unroll
    for (int i2 = 0; i2 < 4; ++i2) {
      int m = mt*16 + mfr + i2;
      stb16_128(ab16, m, col, hbuf[m*HP + col] + acc[i2] + bia);
    }
  }
  __syncthreads();

  // ---- P9: from/to MFMA -> F,T bf16 (alias hbuf) ----
  short* Fb = (short*)hbuf;
  short* Tb = (short*)hbuf + 6144;
  for (int t = wid; t < 48; t += NW) {
    int mt = t >> 3, nt = t & 7;
    int ar = mt*16 + l15, br = nt*16 + l15;
    f32x4 acc = {0.f,0.f,0.f,0.f};
    #pragma unroll
    for (int kk = 0; kk < 2; ++kk) {
      short8 a = ldfrag128(ab16, ar, kk*32 + kfr);
      short8 w = ldfrag128(wAll, br, kk*32 + kfr);
      acc = __builtin_amdgcn_mfma_f32_16x16x32_bf16(a, w, acc, 0, 0, 0);
    }
    int col = nt*16 + l15;
    if (nt < 4) {
      float bia = from_b[col];
      #pragma unroll
      for (int i2 = 0; i2 < 4; ++i2)
        stb16_128(Fb, mt*16 + mfr + i2, col, acc[i2] + bia);
    } else {
      int c2 = col - 64;
      float bia = to_b[c2];
      #pragma unroll
      for (int i2 = 0; i2 < 4; ++i2)
        stb16_128(Tb, mt*16 + mfr + i2, c2, acc[i2] + bia);
    }
  }
  __syncthreads();

  // ---- P10: gram MFMA: G = F @ T^T -> arena fp32 [96][96] ----
  for (int t = wid; t < 36; t += NW) {
    int mt = t / 6, nt = t - mt*6;
    int ar = mt*16 + l15, br = nt*16 + l15;
    f32x4 acc = {0.f,0.f,0.f,0.f};
    #pragma unroll
    for (int kk = 0; kk < 2; ++kk) {
      short8 a = ldfrag128(Fb, ar, kk*32 + kfr);
      short8 w = ldfrag128(Tb, br, kk*32 + kfr);
      acc = __builtin_amdgcn_mfma_f32_16x16x32_bf16(a, w, acc, 0, 0, 0);
    }
    int col = nt*16 + l15;
    #pragma unroll
    for (int i2 = 0; i2 < 4; ++i2)
      G[(mt*16 + mfr + i2)*96 + col] = acc[i2];
  }
  __syncthreads();

  // ---- P11: logits gather ----
  {
    float* ob = out + (size_t)b * NMOV;
    for (int m = tid; m < NMOV; m += NT) {
      ob[m] = G[move_from[m]*96 + move_to[m]] + move_bias[m];
    }
  }
  #undef PALL_ROW
}

extern "C" void kernel_launch(void* const* d_in, const int* in_sizes, int n_in,
                              void* d_out, int out_size, void* d_ws, size_t ws_size,
                              hipStream_t stream) {
  const float* x        = (const float*)d_in[0];
  const float* embed_w  = (const float*)d_in[1];
  const float* embed_b  = (const float*)d_in[2];
  const float* pos      = (const float*)d_in[3];
  const float* in_w     = (const float*)d_in[4];
  const float* in_b     = (const float*)d_in[5];
  const float* out_w    = (const float*)d_in[6];
  const float* out_b    = (const float*)d_in[7];
  const float* ln1_g    = (const float*)d_in[8];
  const float* ln1_b    = (const float*)d_in[9];
  const float* ln2_g    = (const float*)d_in[10];
  const float* ln2_b    = (const float*)d_in[11];
  const float* ff1_w    = (const float*)d_in[12];
  const float* ff1_b    = (const float*)d_in[13];
  const float* ff2_w    = (const float*)d_in[14];
  const float* ff2_b    = (const float*)d_in[15];
  const float* from_w   = (const float*)d_in[16];
  const float* from_b   = (const float*)d_in[17];
  const float* to_w     = (const float*)d_in[18];
  const float* to_b     = (const float*)d_in[19];
  const float* move_bias= (const float*)d_in[20];
  const int*   move_from= (const int*)d_in[21];
  const int*   move_to  = (const int*)d_in[22];

  short* wsb = (short*)d_ws;
  prep_w<<<dim3((W_TOTAL + 255)/256), dim3(256), 0, stream>>>(
      embed_w, in_w, out_w, ff1_w, ff2_w, from_w, to_w, wsb);

  int B = in_sizes[0] / (CIN * 121);
  policy_fused<<<dim3(B), dim3(NT), 0, stream>>>(
      x, embed_b, pos, in_b, out_b,
      ln1_g, ln1_b, ln2_g, ln2_b, ff1_b, ff2_b,
      from_b, to_b, move_bias, move_from, move_to,
      (const short*)wsb, (float*)d_out);
}